// Round 2
// 798.305 us; speedup vs baseline: 1.0128x; 1.0128x over previous
//
#include <hip/hip_runtime.h>

// CombPool2d: x (16,192,224,224) f32, w_avg/w_max (1,192,1,1) f32.
// out = w_avg^2 * avgpool2x2s2(x) + w_max^2 * maxpool2x2s2(x)  -> (16,192,112,112)
//
// Memory-bound: 616.6 MB read + 154.1 MB write, ~8 flops/out elem.
// One thread per 4 output pixels: 4x 16B nt-loads (64 B/lane) + 1x 16B nt-store.
// Grid capped at 2048 blocks, grid-stride loop (G11).
// NOTE: __builtin_nontemporal_* needs a native vector type, not HIP_vector_type.

typedef float f4 __attribute__((ext_vector_type(4)));

#define IN_HW   (224 * 224)
#define OUT_HW  (112 * 112)
#define NCH     192

__global__ __launch_bounds__(256) void combpool2d_kernel(
    const float* __restrict__ x,
    const float* __restrict__ w_avg,
    const float* __restrict__ w_max,
    float* __restrict__ out,
    int n4)  // number of output *quads* = out_size / 4
{
    int stride = gridDim.x * blockDim.x;
    for (int i = blockIdx.x * blockDim.x + threadIdx.x; i < n4; i += stride) {
        // decompose: i -> (bc, oh, ow4) with ow4 in [0,28), oh in [0,112)
        int ow4 = i % 28;          // quad index along output width (112/4)
        int t   = i / 28;
        int oh  = t % 112;
        int bc  = t / 112;         // fused batch*channel index
        int c   = bc % NCH;

        const float* row0 = x + (size_t)bc * IN_HW + (size_t)(2 * oh) * 224;
        const f4* r0 = (const f4*)row0;          // input row 2*oh
        const f4* r1 = (const f4*)(row0 + 224);  // input row 2*oh+1

        f4 a0 = __builtin_nontemporal_load(&r0[2 * ow4]);      // cols 8*ow4..+3
        f4 a1 = __builtin_nontemporal_load(&r0[2 * ow4 + 1]);  // cols 8*ow4+4..+7
        f4 b0 = __builtin_nontemporal_load(&r1[2 * ow4]);
        f4 b1 = __builtin_nontemporal_load(&r1[2 * ow4 + 1]);

        float ca = w_avg[c]; ca *= ca;
        float cm = w_max[c]; cm *= cm;

        f4 o;
        o.x = ca * (0.25f * ((a0.x + a0.y) + (b0.x + b0.y)))
            + cm * fmaxf(fmaxf(a0.x, a0.y), fmaxf(b0.x, b0.y));
        o.y = ca * (0.25f * ((a0.z + a0.w) + (b0.z + b0.w)))
            + cm * fmaxf(fmaxf(a0.z, a0.w), fmaxf(b0.z, b0.w));
        o.z = ca * (0.25f * ((a1.x + a1.y) + (b1.x + b1.y)))
            + cm * fmaxf(fmaxf(a1.x, a1.y), fmaxf(b1.x, b1.y));
        o.w = ca * (0.25f * ((a1.z + a1.w) + (b1.z + b1.w)))
            + cm * fmaxf(fmaxf(a1.z, a1.w), fmaxf(b1.z, b1.w));

        f4* orow = (f4*)(out + (size_t)bc * OUT_HW + (size_t)oh * 112);
        __builtin_nontemporal_store(o, &orow[ow4]);
    }
}

extern "C" void kernel_launch(void* const* d_in, const int* in_sizes, int n_in,
                              void* d_out, int out_size, void* d_ws, size_t ws_size,
                              hipStream_t stream) {
    const float* x     = (const float*)d_in[0];
    const float* w_avg = (const float*)d_in[1];
    const float* w_max = (const float*)d_in[2];
    float* out = (float*)d_out;

    int n4 = out_size / 4;                 // 9,633,792 work-items
    int block = 256;
    int grid = (n4 + block - 1) / block;
    if (grid > 2048) grid = 2048;          // grid-stride; persistent waves (G11)
    combpool2d_kernel<<<grid, block, 0, stream>>>(x, w_avg, w_max, out, n4);
}